// Round 1
// baseline (497.956 us; speedup 1.0000x reference)
//
#include <hip/hip_runtime.h>

#define D 48

__global__ __launch_bounds__(256) void zero_kernel(int* __restrict__ p, int n) {
    int i = blockIdx.x * 256 + threadIdx.x;
    if (i < n) p[i] = 0;
}

__global__ __launch_bounds__(256) void hist_kernel(const int* __restrict__ vidx,
                                                   int* __restrict__ count, int E) {
    int e = blockIdx.x * 256 + threadIdx.x;
    if (e < E) atomicAdd(&count[vidx[e]], 1);
}

// Single-block exclusive scan of `count[0..n)` -> row_start, cursor.
__global__ __launch_bounds__(1024) void scan_kernel(const int* __restrict__ count,
                                                    int* __restrict__ row_start,
                                                    int* __restrict__ cursor,
                                                    int n, int n_edges) {
    __shared__ int lds[1024];
    int t = threadIdx.x;
    int chunk = (n + 1023) / 1024;
    int base = t * chunk;
    int lim = min(base + chunk, n);
    int sum = 0;
    for (int j = base; j < lim; ++j) sum += count[j];
    lds[t] = sum;
    __syncthreads();
    for (int s = 1; s < 1024; s <<= 1) {
        int add = (t >= s) ? lds[t - s] : 0;
        __syncthreads();
        lds[t] += add;
        __syncthreads();
    }
    int off = lds[t] - sum;  // exclusive prefix for this chunk
    for (int j = base; j < lim; ++j) {
        row_start[j] = off;
        cursor[j] = off;
        off += count[j];
    }
    if (t == 1023) row_start[n] = n_edges;
}

__global__ __launch_bounds__(256) void scatter_kernel(const int* __restrict__ uidx,
                                                      const int* __restrict__ vidx,
                                                      int* __restrict__ cursor,
                                                      int* __restrict__ u_list,
                                                      int* __restrict__ e_list, int E) {
    int e = blockIdx.x * 256 + threadIdx.x;
    if (e < E) {
        int v = vidx[e];
        int pos = atomicAdd(&cursor[v], 1);
        u_list[pos] = uidx[e];
        e_list[pos] = e;
    }
}

// One thread per (node, feature). Three serial passes over the node's edges:
// max, exp-sum, normalize+write. All src gathers are L2-resident (src = 9.6MB).
__global__ __launch_bounds__(256) void seg_softmax_kernel(
    const float* __restrict__ src,
    const int* __restrict__ row_start,
    const int* __restrict__ u_list,
    const int* __restrict__ e_list,
    float* __restrict__ out, int n_nodes) {
    int gid = blockIdx.x * 256 + threadIdx.x;
    int total = n_nodes * D;
    if (gid >= total) return;
    int node = gid / D;
    int d = gid - node * D;
    int beg = row_start[node];
    int end = row_start[node + 1];
    const float* __restrict__ sp = src + d;

    // pass 1: max
    float m = -INFINITY;
    int i = beg;
    for (; i + 4 <= end; i += 4) {
        int u0 = u_list[i], u1 = u_list[i + 1], u2 = u_list[i + 2], u3 = u_list[i + 3];
        float x0 = sp[u0 * D], x1 = sp[u1 * D], x2 = sp[u2 * D], x3 = sp[u3 * D];
        m = fmaxf(fmaxf(fmaxf(m, x0), x1), fmaxf(x2, x3));
    }
    for (; i < end; ++i) m = fmaxf(m, sp[u_list[i] * D]);

    // pass 2: sum of exp
    float s = 0.f;
    i = beg;
    for (; i + 4 <= end; i += 4) {
        int u0 = u_list[i], u1 = u_list[i + 1], u2 = u_list[i + 2], u3 = u_list[i + 3];
        float x0 = sp[u0 * D], x1 = sp[u1 * D], x2 = sp[u2 * D], x3 = sp[u3 * D];
        s += __expf(x0 - m) + __expf(x1 - m) + __expf(x2 - m) + __expf(x3 - m);
    }
    for (; i < end; ++i) s += __expf(sp[u_list[i] * D] - m);

    float inv = 1.0f / s;

    // pass 3: write normalized values
    i = beg;
    for (; i + 4 <= end; i += 4) {
        int u0 = u_list[i], u1 = u_list[i + 1], u2 = u_list[i + 2], u3 = u_list[i + 3];
        int e0 = e_list[i], e1 = e_list[i + 1], e2 = e_list[i + 2], e3 = e_list[i + 3];
        float x0 = sp[u0 * D], x1 = sp[u1 * D], x2 = sp[u2 * D], x3 = sp[u3 * D];
        out[e0 * D + d] = __expf(x0 - m) * inv;
        out[e1 * D + d] = __expf(x1 - m) * inv;
        out[e2 * D + d] = __expf(x2 - m) * inv;
        out[e3 * D + d] = __expf(x3 - m) * inv;
    }
    for (; i < end; ++i) {
        int u = u_list[i];
        int e = e_list[i];
        out[e * D + d] = __expf(sp[u * D] - m) * inv;
    }
}

extern "C" void kernel_launch(void* const* d_in, const int* in_sizes, int n_in,
                              void* d_out, int out_size, void* d_ws, size_t ws_size,
                              hipStream_t stream) {
    const float* src = (const float*)d_in[0];
    const int* index = (const int*)d_in[1];
    int N = in_sizes[0] / D;
    int E = in_sizes[1] / 2;
    const int* uidx = index;      // row 0: gather (source) index
    const int* vidx = index + E;  // row 1: scatter (dest/segment) index

    char* ws = (char*)d_ws;
    int* count = (int*)ws;      ws += sizeof(int) * (size_t)N;
    int* row_start = (int*)ws;  ws += sizeof(int) * (size_t)(N + 1);
    int* cursor = (int*)ws;     ws += sizeof(int) * (size_t)N;
    int* u_list = (int*)ws;     ws += sizeof(int) * (size_t)E;
    int* e_list = (int*)ws;     ws += sizeof(int) * (size_t)E;
    float* out = (float*)d_out;

    zero_kernel<<<(N + 255) / 256, 256, 0, stream>>>(count, N);
    hist_kernel<<<(E + 255) / 256, 256, 0, stream>>>(vidx, count, E);
    scan_kernel<<<1, 1024, 0, stream>>>(count, row_start, cursor, N, E);
    scatter_kernel<<<(E + 255) / 256, 256, 0, stream>>>(uidx, vidx, cursor, u_list, e_list, E);

    int total = N * D;
    seg_softmax_kernel<<<(total + 255) / 256, 256, 0, stream>>>(src, row_start, u_list, e_list,
                                                                out, N);
}